// Round 6
// baseline (45.250 us; speedup 1.0000x reference)
//
#include <hip/hip_runtime.h>

#define BS 16
#define S  256
#define H  1024
#define T  32

// ws layout (floats): ps[512] | p1[4096*32] | p2[4096*32]
#define PS_OFF 0
#define P1_OFF 512
#define P2_OFF (P1_OFF + BS * S * T)

typedef __bf16 bf16x8 __attribute__((ext_vector_type(8)));
typedef float  f32x4  __attribute__((ext_vector_type(4)));

// ---------------------------------------------------------------------------
// Kernel A (single pass, no LDS, no barrier):
//   blk < 256: GEMM. m-tile = 16 rows (m0 = blk*16); wave w owns output cols
//     [16w,16w+16). Full K=1024 in one wave: 32 MFMAs, 4 independent acc
//     chains for ILP. A-frags read straight from global E (4x L2 re-read per
//     block is ~free); B-frags streamed from L2-hot W with in-reg f32->bf16.
//   blk in [256,384): ps — one wave per (b,t), coalesced + shfl_xor reduce.
// ---------------------------------------------------------------------------
__global__ __launch_bounds__(256) void gemm_ps(
    const float* __restrict__ seq, const float* __restrict__ E,
    const float* __restrict__ W, const float* __restrict__ bias,
    float* __restrict__ ws)
{
    const int tid = threadIdx.x;
    const int lane = tid & 63, wv = tid >> 6;

    if (blockIdx.x >= 256) {
        // ---- ps[b,t] = seq[b,:] . W[t,2H:3H] + bias[t], wave-parallel ----
        float* ps = ws + PS_OFF;
        const int o = (blockIdx.x - 256) * 4 + wv;    // 0..511
        const int bb = o >> 5, t = o & 31;
        const float4* sp = (const float4*)(seq + (size_t)bb * H) + lane * 4;
        const float4* wp = (const float4*)(W + (size_t)t * (3 * H) + 2 * H) + lane * 4;
        float acc = 0.f;
        #pragma unroll
        for (int k = 0; k < 4; ++k) {
            float4 a = sp[k], w = wp[k];
            acc += a.x * w.x + a.y * w.y + a.z * w.z + a.w * w.w;
        }
        #pragma unroll
        for (int m = 32; m >= 1; m >>= 1) acc += __shfl_xor(acc, m);
        if (lane == 0) ps[o] = acc + bias[t];
        return;
    }

    const int m0 = blockIdx.x * 16;
    const int nb = wv * 16;
    const int wrow = nb + (lane & 15);                // output col 0..63
    const int ksub = (lane >> 4) * 8;                 // k sub-offset 0/8/16/24

    // B source: W row wrow&31, block 0 (p1) or 1 (p2). A source: E row lane&15.
    const float* wbase = W + (size_t)(wrow & 31) * (3 * H) + ((wrow >> 5) ? H : 0) + ksub;
    const float* ebase = E + (size_t)(m0 + (lane & 15)) * H + ksub;

    f32x4 acc[4] = {{0.f,0.f,0.f,0.f},{0.f,0.f,0.f,0.f},
                    {0.f,0.f,0.f,0.f},{0.f,0.f,0.f,0.f}};

    #pragma unroll 8
    for (int s = 0; s < 32; ++s) {
        float4 al = *(const float4*)(ebase + s * 32);
        float4 ah = *(const float4*)(ebase + s * 32 + 4);
        float4 bl = *(const float4*)(wbase + s * 32);
        float4 bh = *(const float4*)(wbase + s * 32 + 4);
        bf16x8 a, b;
        a[0] = (__bf16)al.x; a[1] = (__bf16)al.y; a[2] = (__bf16)al.z; a[3] = (__bf16)al.w;
        a[4] = (__bf16)ah.x; a[5] = (__bf16)ah.y; a[6] = (__bf16)ah.z; a[7] = (__bf16)ah.w;
        b[0] = (__bf16)bl.x; b[1] = (__bf16)bl.y; b[2] = (__bf16)bl.z; b[3] = (__bf16)bl.w;
        b[4] = (__bf16)bh.x; b[5] = (__bf16)bh.y; b[6] = (__bf16)bh.z; b[7] = (__bf16)bh.w;
        acc[s & 3] = __builtin_amdgcn_mfma_f32_16x16x32_bf16(a, b, acc[s & 3], 0, 0, 0);
    }
    f32x4 sum = (acc[0] + acc[1]) + (acc[2] + acc[3]);

    // ---- store: D layout col=lane&15, row=(lane>>4)*4+r; dst wave-uniform ----
    const int orow = (lane >> 4) * 4;
    float* dst = (nb < 32) ? (ws + P1_OFF) : (ws + P2_OFF);
    const int c = wrow & 31;
    #pragma unroll
    for (int r = 0; r < 4; ++r)
        dst[(size_t)(m0 + orow + r) * T + c] = sum[r];
}

// ---------------------------------------------------------------------------
// Kernel B: out[b,i,j,t] = (p1[b,i,t] + ps[b,t]) + p2[b,j,t]
// ---------------------------------------------------------------------------
__global__ __launch_bounds__(256) void bcast_add(
    const float* __restrict__ ws, float* __restrict__ out)
{
    const int blk = blockIdx.x;
    const int b = blk >> 8, i = blk & 255;
    const int tid = threadIdx.x;

    __shared__ __align__(16) float s1[32];
    if (tid < 32)
        s1[tid] = (ws + P1_OFF)[(size_t)(b * S + i) * T + tid]
                + (ws + PS_OFF)[b * T + tid];
    __syncthreads();

    const float4 s = *(const float4*)&s1[(tid & 7) * 4];
    const float4* p2v = (const float4*)(ws + P2_OFF) + (size_t)b * (S * T / 4);
    float4* ov = (float4*)out + (size_t)(b * S + i) * (S * T / 4);

    #pragma unroll
    for (int k = tid; k < S * T / 4; k += 256) {
        float4 v = p2v[k];
        float4 r;
        r.x = v.x + s.x; r.y = v.y + s.y; r.z = v.z + s.z; r.w = v.w + s.w;
        ov[k] = r;
    }
}

extern "C" void kernel_launch(void* const* d_in, const int* in_sizes, int n_in,
                              void* d_out, int out_size, void* d_ws, size_t ws_size,
                              hipStream_t stream)
{
    const float* seq  = (const float*)d_in[0];   // (16,1024)
    const float* E    = (const float*)d_in[1];   // (16,256,1024)
    const float* W    = (const float*)d_in[2];   // (32,3072)
    const float* bias = (const float*)d_in[3];   // (32,)
    float* out = (float*)d_out;                  // (16,256,256,32) f32
    float* ws  = (float*)d_ws;                   // ~1.05 MB used

    gemm_ps<<<384, 256, 0, stream>>>(seq, E, W, bias, ws);
    bcast_add<<<BS * S, 256, 0, stream>>>(ws, out);
}